// Round 13
// baseline (13172.847 us; speedup 1.0000x reference)
//
#include <hip/hip_runtime.h>

#define H     512
#define BQ    64
#define TT    512
#define CIN   64
#define COUT  64
#define NWG   132           // 64 stage-A + 64 stage-B + 4 FC
#define THREADS 256
#define RSLOTS 32           // ring slots; address reuse period = 32 steps

typedef unsigned int  uint;
typedef unsigned short ushort;
typedef short bf16x8 __attribute__((ext_vector_type(8)));
typedef float f32x4  __attribute__((ext_vector_type(4)));

// LDS layout (bytes): gate-interleaved weight pair-tiles, bf16 hi+lo
#define GH_BASE   0          // 2 tiles K=512 : 64 KB
#define GI_BASE   65536      // 2 tiles K<=512: 64 KB
#define GI0_BASE  131072     // 2 tiles K=64  :  8 KB  (dec-A t=0 only)
#define SMEM_SIZE 139264

// ws layout (bytes)
#define WS_FLAGS  0          // 132 flags, 64B apart: one writer per line
#define WS_GEN    8448       // generation counter, own line, written by WG0 only
#define WS_BAR_SZ 16384
#define WS_BP     16384      // b' f32[1536]
#define WS_F0H    22528      // f0 hi bf16[64][64]
#define WS_F0L    30720
#define WS_H0RH   65536      // h0 ring [32][64][512] bf16 hi : 2 MB
#define WS_H0RL   2162688
#define WS_H1RH   4259840
#define WS_H1RL   6356992
#define WS_M      8454144    // M f32[1536][512]

// slot offset in ushorts for absolute step s
#define SLOT(s)   (((s) & (RSLOTS-1)) * 32768)

struct Params {
  const float *x, *f0;
  const float *eWih0,*eWhh0,*ebih0,*ebhh0,*eWih1,*eWhh1,*ebih1,*ebhh1;
  const float *dWih0,*dWhh0,*dbih0,*dbhh0,*dWih1,*dWhh1,*dbih1,*dbhh1;
  const float *fcW,*fcb;
  float* out;
  char* ws;
};

__device__ __forceinline__ ushort f2bf(float v){
  uint b = __float_as_uint(v);
  return (ushort)((b + 0x7FFFu + ((b >> 16) & 1u)) >> 16);
}
__device__ __forceinline__ float bf2f(ushort u){ return __uint_as_float(((uint)u) << 16); }

// ---------------- grid barrier: two-hop LEADER scheme, fence-free polls.
// Rationale (R13): R11/R12 all-to-all polling issues ~17K distinct-line LLC
// requests per 100ns grid-wide (132 WGs x 132 lines) -> transaction congestion
// at the coherence point inflates publish->observe latency to ~7.7us.
// Here: each WG's tid0 publishes its own 64B-strided flag (one writer/line),
// ONLY WG0 polls the 132 flags, then publishes a generation counter; the other
// 131 WGs poll that single read-only line. Poll traffic drops ~100x for one
// extra hop (~+0.5us). Polls stay RELAXED (coherence-point reads, never stale
// — R11 lesson: no in-loop fences; 1024-iter parachute only). Ring coherence
// unchanged: write-through relaxed agent stores, plain cached reads,
// acquire-inv every 16 rounds (reuse window 32).
__device__ __forceinline__ void gbar(uint* flags, uint* gen, uint r, int wg, int tid,
                                     bool rel, bool inv){
  __syncthreads();                                   // ring stores drained (vmcnt 0)
  if (tid == 0){
    if (rel) __builtin_amdgcn_fence(__ATOMIC_RELEASE, "agent");   // flush plain-stored staging
    __hip_atomic_store(&flags[wg*16], r, __ATOMIC_RELAXED, __HIP_MEMORY_SCOPE_AGENT);
  }
  asm volatile("" ::: "memory");
  if (wg == 0){
    if (tid < NWG){
      uint it = 0;
      while (__hip_atomic_load(&flags[tid*16], __ATOMIC_RELAXED, __HIP_MEMORY_SCOPE_AGENT) < r){
        __builtin_amdgcn_s_sleep(1);
        if ((++it & 1023u) == 0u) __builtin_amdgcn_fence(__ATOMIC_ACQUIRE, "agent");  // parachute
      }
    }
    __syncthreads();
    if (tid == 0)
      __hip_atomic_store(gen, r, __ATOMIC_RELAXED, __HIP_MEMORY_SCOPE_AGENT);
  } else {
    if (tid == 0){
      uint it = 0;
      while (__hip_atomic_load(gen, __ATOMIC_RELAXED, __HIP_MEMORY_SCOPE_AGENT) < r){
        __builtin_amdgcn_s_sleep(1);
        if ((++it & 1023u) == 0u) __builtin_amdgcn_fence(__ATOMIC_ACQUIRE, "agent");  // parachute
      }
    }
  }
  __syncthreads();
  if (inv) __builtin_amdgcn_fence(__ATOMIC_ACQUIRE, "agent");     // periodic L1/L2 invalidate
}

// ---------------- pack 2 gate-interleaved pair-tiles (32 slots x K) into LDS
template<int K>
__device__ void packW(char* lds, int base, const float* __restrict__ W, int colbase, int tid){
  for (int e = tid; e < 32*K; e += THREADS){
    int S = e / K, k = e - S*K;
    int gate = S & 3, hcl = S >> 2;
    float v = (gate < 3) ? W[(gate*H + colbase + hcl)*K + k] : 0.f;
    ushort hi = f2bf(v);
    ushort lo = f2bf(v - bf2f(hi));
    int tau = S >> 4, s = S & 15;
    int off = ((s*K + k)*2) ^ ((s & 7) << 4);
    char* tb = lds + base + tau*(16*K*4);
    *(ushort*)(tb + off) = hi;
    *(ushort*)(tb + 16*K*2 + off) = lo;
  }
}

__device__ void packFC(char* lds, const float* __restrict__ fcW, int colbase, int tid){
  for (int e = tid; e < 16*512; e += THREADS){
    int s = e >> 9, k = e & 511;
    float v = fcW[(colbase + s)*512 + k];
    ushort hi = f2bf(v);
    ushort lo = f2bf(v - bf2f(hi));
    int off = ((s*512 + k)*2) ^ ((s & 7) << 4);
    *(ushort*)(lds + off) = hi;
    *(ushort*)(lds + 16*512*2 + off) = lo;
  }
}

__device__ __forceinline__ void loadBias(const float* __restrict__ src, int colbase, int c, float* b){
#pragma unroll
  for (int tau = 0; tau < 2; ++tau){
    int gate = c & 3, hcl = 4*tau + (c >> 2);
    b[tau] = (gate < 3) ? src[gate*H + colbase + hcl] : 0.f;
  }
}

__device__ __forceinline__ void loadHold(const ushort* rh, const ushort* rl, int colb,
                                         int m, int lane, f32x4* hold){
  int c = lane & 15, g = lane >> 4;
#pragma unroll
  for (int tau = 0; tau < 2; ++tau){
    int col = colb + 4*tau + (c >> 2);
#pragma unroll
    for (int q = 0; q < 4; ++q){
      int row = m*16 + g*4 + q;
      hold[tau][q] = bf2f(rh[row*H + col]) + bf2f(rl[row*H + col]);
    }
  }
}

// ---------------- 64xNTAU*16 GEMM tile, split-bf16 3-term, weights from LDS
// A (hi/lo): bf16 [64][K] row-major, plain cached loads (L2-shared per XCD),
// all hoisted so the stream pipelines behind one latency.
template<int NTAU, int K>
__device__ __forceinline__ void gemm(const ushort* __restrict__ AH, const ushort* __restrict__ AL,
                                     const char* lds, int base, const float* bias,
                                     int m, int lane, f32x4* pre){
  const int c = lane & 15, g = lane >> 4;
  const int rowoff = (m*16 + c)*K + g*8;
  constexpr int NK = K/32;
  bf16x8 ahv[NK], alv[NK];
#pragma unroll
  for (int kc = 0; kc < NK; ++kc){
    ahv[kc] = *(const bf16x8*)(AH + rowoff + kc*32);
    alv[kc] = *(const bf16x8*)(AL + rowoff + kc*32);
  }
  f32x4 a1[NTAU], a2[NTAU];
#pragma unroll
  for (int tau = 0; tau < NTAU; ++tau){
    a1[tau] = f32x4{bias[tau], bias[tau], bias[tau], bias[tau]};
    a2[tau] = f32x4{0.f, 0.f, 0.f, 0.f};
  }
#pragma unroll
  for (int kc = 0; kc < NK; ++kc){
    const int off = ((c*K + kc*32 + g*8)*2) ^ ((c & 7) << 4);
#pragma unroll
    for (int tau = 0; tau < NTAU; ++tau){
      const char* tb = lds + base + tau*(16*K*4);
      bf16x8 wh = *(const bf16x8*)(tb + off);
      bf16x8 wl = *(const bf16x8*)(tb + 16*K*2 + off);
      a1[tau] = __builtin_amdgcn_mfma_f32_16x16x32_bf16(ahv[kc], wh, a1[tau], 0, 0, 0);
      a2[tau] = __builtin_amdgcn_mfma_f32_16x16x32_bf16(ahv[kc], wl, a2[tau], 0, 0, 0);
      a2[tau] = __builtin_amdgcn_mfma_f32_16x16x32_bf16(alv[kc], wh, a2[tau], 0, 0, 0);
    }
  }
#pragma unroll
  for (int tau = 0; tau < NTAU; ++tau) pre[tau] = a1[tau] + a2[tau];
}

// ---------------- GRU gates + hidden store (write-through relaxed agent atomics)
__device__ __forceinline__ void gates_store(const f32x4* pgi, const f32x4* pgh, f32x4* hold,
                                            ushort* __restrict__ outH, ushort* __restrict__ outL,
                                            int colb, int m, int lane){
  const int c = lane & 15, g = lane >> 4;
#pragma unroll
  for (int tau = 0; tau < 2; ++tau){
    f32x4 s, n, hn, rsh, zsh;
#pragma unroll
    for (int q = 0; q < 4; ++q) s[q] = 1.f / (1.f + expf(-(pgi[tau][q] + pgh[tau][q])));
#pragma unroll
    for (int q = 0; q < 4; ++q) rsh[q] = __shfl_xor(s[q], 2, 64);
#pragma unroll
    for (int q = 0; q < 4; ++q) zsh[q] = __shfl_xor(s[q], 3, 64);
#pragma unroll
    for (int q = 0; q < 4; ++q) n[q] = tanhf(pgi[tau][q] + rsh[q]*pgh[tau][q]);
#pragma unroll
    for (int q = 0; q < 4; ++q) hn[q] = (1.f - zsh[q])*n[q] + zsh[q]*hold[tau][q];
    hold[tau] = hn;
    if ((c & 3) == 2){
      const int col = colb + 4*tau + (c >> 2);
#pragma unroll
      for (int q = 0; q < 4; ++q){
        const int row = m*16 + g*4 + q;
        ushort hi = f2bf(hn[q]);
        ushort lo = f2bf(hn[q] - bf2f(hi));
        __hip_atomic_store(&outH[row*H + col], hi, __ATOMIC_RELAXED, __HIP_MEMORY_SCOPE_AGENT);
        __hip_atomic_store(&outL[row*H + col], lo, __ATOMIC_RELAXED, __HIP_MEMORY_SCOPE_AGENT);
      }
    }
  }
}

__device__ __forceinline__ f32x4 bc4(float v){ return f32x4{v, v, v, v}; }

__global__ __launch_bounds__(THREADS, 1) void rnn_persist(Params p){
  extern __shared__ char smem[];
  char* ws = p.ws;
  uint* flags = (uint*)(ws + WS_FLAGS);
  uint* gen   = (uint*)(ws + WS_GEN);
  float*  bp   = (float*)(ws + WS_BP);
  ushort* f0H  = (ushort*)(ws + WS_F0H);
  ushort* f0L  = (ushort*)(ws + WS_F0L);
  ushort* h0rH = (ushort*)(ws + WS_H0RH);
  ushort* h0rL = (ushort*)(ws + WS_H0RL);
  ushort* h1rH = (ushort*)(ws + WS_H1RH);
  ushort* h1rL = (ushort*)(ws + WS_H1RL);
  float*  Mw   = (float*)(ws + WS_M);
  ushort* xTH  = (ushort*)(void*)p.out;              // staged in d_out; dead before FC writes
  ushort* xTL  = xTH + TT*BQ*CIN;

  const int wg = blockIdx.x, tid = threadIdx.x;
  const int wid = tid >> 6, lane = tid & 63;
  const int c = lane & 15;
  const int gtid = wg*THREADS + tid;
  const int gstride = NWG*THREADS;
  uint bno = 0;

  // ================= prepass: xT (transpose+split), f0, M = dWih0@fcW, b'
  for (int e = gtid; e < TT*BQ*CIN; e += gstride){
    int t = e >> 12, b = (e >> 6) & 63, cc = e & 63;
    float v = p.x[(b*CIN + cc)*TT + t];
    ushort hi = f2bf(v);
    xTH[e] = hi; xTL[e] = f2bf(v - bf2f(hi));
  }
  for (int e = gtid; e < BQ*COUT; e += gstride){
    float v = p.f0[e];
    ushort hi = f2bf(v);
    f0H[e] = hi; f0L[e] = f2bf(v - bf2f(hi));
  }
  {
    const int total = 1536*512;
    const int per = (total + gstride - 1) / gstride;
    const int start = gtid * per;
    for (int i = 0; i < per; ++i){
      int e = start + i;
      if (e >= total) break;
      int rr = e >> 9, q = e & 511;
      float acc = 0.f;
      for (int k = 0; k < 64; ++k) acc += p.dWih0[rr*64 + k] * p.fcW[k*512 + q];
      Mw[e] = acc;
    }
  }
  for (int e = gtid; e < 1536; e += gstride){
    float acc = p.dbih0[e];
    for (int k = 0; k < 64; ++k) acc += p.dWih0[e*64 + k] * p.fcb[k];
    bp[e] = acc;
  }
  gbar(flags, gen, ++bno, wg, tid, true, true);   // release staging + start clean

  // ================= pack encoder weights into LDS, load biases
  const bool isA = (wg < 64), isB = (wg >= 64 && wg < 128);
  const int colb = isA ? wg*8 : (wg - 64)*8;
  float bgi[2] = {0.f,0.f}, bgh[2] = {0.f,0.f}, bgi0[2] = {0.f,0.f}, bfc = 0.f;
  f32x4 hold[2]; hold[0] = bc4(0.f); hold[1] = bc4(0.f);
  int fccol = 0;
  if (isA){
    packW<64 >(smem, GI_BASE, p.eWih0, colb, tid);
    packW<512>(smem, GH_BASE, p.eWhh0, colb, tid);
    loadBias(p.ebih0, colb, c, bgi); loadBias(p.ebhh0, colb, c, bgh);
  } else if (isB){
    packW<512>(smem, GI_BASE, p.eWih1, colb, tid);
    packW<512>(smem, GH_BASE, p.eWhh1, colb, tid);
    loadBias(p.ebih1, colb, c, bgi); loadBias(p.ebhh1, colb, c, bgh);
  } else {
    fccol = (wg - 128)*16;
    packFC(smem, p.fcW, fccol, tid);
    bfc = p.fcb[fccol + c];
  }
  gbar(flags, gen, ++bno, wg, tid, false, false);

  // ================= encoder: 513 pipelined rounds (A: L0 @ t=r ; B: L1 @ t=r-1)
  for (int r = 0; r <= TT; ++r){
    if (isA && r < TT){
      const int t = r;
      f32x4 pgi[2], pgh[2];
      if (t > 0)
        gemm<2,512>(h0rH + SLOT(t-1), h0rL + SLOT(t-1), smem, GH_BASE, bgh, wid, lane, pgh);
      else { pgh[0] = bc4(bgh[0]); pgh[1] = bc4(bgh[1]); }
      gemm<2,64>(xTH + t*4096, xTL + t*4096, smem, GI_BASE, bgi, wid, lane, pgi);
      gates_store(pgi, pgh, hold, h0rH + SLOT(t), h0rL + SLOT(t), colb, wid, lane);
    } else if (isB && r >= 1){
      const int t = r - 1;
      f32x4 pgi[2], pgh[2];
      if (t > 0)
        gemm<2,512>(h1rH + SLOT(t-1), h1rL + SLOT(t-1), smem, GH_BASE, bgh, wid, lane, pgh);
      else { pgh[0] = bc4(bgh[0]); pgh[1] = bc4(bgh[1]); }
      gemm<2,512>(h0rH + SLOT(t), h0rL + SLOT(t), smem, GI_BASE, bgi, wid, lane, pgi);
      gates_store(pgi, pgh, hold, h1rH + SLOT(t), h1rL + SLOT(t), colb, wid, lane);
    }
    ++bno;
    gbar(flags, gen, bno, wg, tid, false, (bno & 15u) == 0u);
  }

  // ================= repack decoder weights, reload state (enc finals = step 511)
  if (isA){
    packW<512>(smem, GH_BASE, p.dWhh0, colb, tid);
    packW<512>(smem, GI_BASE, Mw,      colb, tid);   // folded FC->L0 input weights
    packW<64 >(smem, GI0_BASE, p.dWih0, colb, tid);
    loadBias(bp,      colb, c, bgi);
    loadBias(p.dbhh0, colb, c, bgh);
    loadBias(p.dbih0, colb, c, bgi0);
    loadHold(h0rH + SLOT(511), h0rL + SLOT(511), colb, wid, lane, hold);
  } else if (isB){
    packW<512>(smem, GI_BASE, p.dWih1, colb, tid);
    packW<512>(smem, GH_BASE, p.dWhh1, colb, tid);
    loadBias(p.dbih1, colb, c, bgi); loadBias(p.dbhh1, colb, c, bgh);
    loadHold(h1rH + SLOT(511), h1rL + SLOT(511), colb, wid, lane, hold);
  }
  gbar(flags, gen, ++bno, wg, tid, false, true);     // phase transition: force inv

  // ================= decoder: 1025 rounds; A fires even r (step g=512+t), B odd.
  // Off-parity rounds precompute the recurrent half (operand one round old).
  f32x4 pgh_s[2]; pgh_s[0] = bc4(0.f); pgh_s[1] = bc4(0.f);
  for (int r = 0; r <= 2*TT; ++r){
    if (isA){
      if (r == 0){
        gemm<2,512>(h0rH + SLOT(511), h0rL + SLOT(511), smem, GH_BASE, bgh, wid, lane, pgh_s);
        f32x4 pgi[2];
        gemm<2,64>(f0H, f0L, smem, GI0_BASE, bgi0, wid, lane, pgi);
        gates_store(pgi, pgh_s, hold, h0rH + SLOT(512), h0rL + SLOT(512), colb, wid, lane);
      } else if (r & 1){
        const int t = (r + 1) >> 1;                  // prefetch gh for next step: h0^{511+t}
        if (t < TT) gemm<2,512>(h0rH + SLOT(511+t), h0rL + SLOT(511+t), smem, GH_BASE, bgh, wid, lane, pgh_s);
      } else {
        const int t = r >> 1;
        if (t < TT){
          f32x4 pgi[2];
          gemm<2,512>(h1rH + SLOT(511+t), h1rL + SLOT(511+t), smem, GI_BASE, bgi, wid, lane, pgi);
          gates_store(pgi, pgh_s, hold, h0rH + SLOT(512+t), h0rL + SLOT(512+t), colb, wid, lane);
        }
      }
    } else if (isB){
      if (!(r & 1)){
        const int t = r >> 1;                        // prefetch gh: h1^{511+t}
        if (t < TT) gemm<2,512>(h1rH + SLOT(511+t), h1rL + SLOT(511+t), smem, GH_BASE, bgh, wid, lane, pgh_s);
      } else {
        const int t = r >> 1;
        f32x4 pgi[2];
        gemm<2,512>(h0rH + SLOT(512+t), h0rL + SLOT(512+t), smem, GI_BASE, bgi, wid, lane, pgi);
        gates_store(pgi, pgh_s, hold, h1rH + SLOT(512+t), h1rL + SLOT(512+t), colb, wid, lane);
      }
    } else {
      if (!(r & 1) && r >= 2){
        const int t = (r - 2) >> 1;                  // FC head, 2 rounds late: h1^{512+t}
        f32x4 pre[1];
        gemm<1,512>(h1rH + SLOT(512+t), h1rL + SLOT(512+t), smem, 0, &bfc, wid, lane, pre);
        const int outcol = fccol + c, gq = lane >> 4;
#pragma unroll
        for (int q = 0; q < 4; ++q){
          const int row = wid*16 + gq*4 + q;
          p.out[(row*COUT + outcol)*TT + t] = pre[0][q];
        }
      }
    }
    ++bno;
    gbar(flags, gen, bno, wg, tid, false, (bno & 15u) == 0u);
  }
}

extern "C" void kernel_launch(void* const* d_in, const int* in_sizes, int n_in,
                              void* d_out, int out_size, void* d_ws, size_t ws_size,
                              hipStream_t stream){
  Params p;
  p.x     = (const float*)d_in[0];  p.f0    = (const float*)d_in[1];
  p.eWih0 = (const float*)d_in[2];  p.eWhh0 = (const float*)d_in[3];
  p.ebih0 = (const float*)d_in[4];  p.ebhh0 = (const float*)d_in[5];
  p.eWih1 = (const float*)d_in[6];  p.eWhh1 = (const float*)d_in[7];
  p.ebih1 = (const float*)d_in[8];  p.ebhh1 = (const float*)d_in[9];
  p.dWih0 = (const float*)d_in[10]; p.dWhh0 = (const float*)d_in[11];
  p.dbih0 = (const float*)d_in[12]; p.dbhh0 = (const float*)d_in[13];
  p.dWih1 = (const float*)d_in[14]; p.dWhh1 = (const float*)d_in[15];
  p.dbih1 = (const float*)d_in[16]; p.dbhh1 = (const float*)d_in[17];
  p.fcW   = (const float*)d_in[18]; p.fcb   = (const float*)d_in[19];
  p.out = (float*)d_out;
  p.ws  = (char*)d_ws;

  hipFuncSetAttribute((const void*)rnn_persist, hipFuncAttributeMaxDynamicSharedMemorySize, SMEM_SIZE);
  hipMemsetAsync(d_ws, 0, WS_BAR_SZ, stream);   // reset barrier flags + gen each launch
  hipLaunchKernelGGL(rnn_persist, dim3(NWG), dim3(THREADS), SMEM_SIZE, stream, p);
}

// Round 14
// 10535.632 us; speedup vs baseline: 1.2503x; 1.2503x over previous
//
#include <hip/hip_runtime.h>

#define H     512
#define BQ    64
#define TT    512
#define CIN   64
#define COUT  64
#define NWG   132           // 64 stage-A + 64 stage-B + 4 FC
#define THREADS 256
#define RSLOTS 32           // ring slots; address reuse period = 32 steps

typedef unsigned int  uint;
typedef unsigned short ushort;
typedef unsigned long long u64;
typedef short bf16x8 __attribute__((ext_vector_type(8)));
typedef float f32x4  __attribute__((ext_vector_type(4)));

// LDS layout (bytes): gate-interleaved weight pair-tiles, bf16 hi+lo
#define GH_BASE   0          // 2 tiles K=512 : 64 KB
#define GI_BASE   65536      // 2 tiles K<=512: 64 KB
#define GI0_BASE  131072     // 2 tiles K=64  :  8 KB  (dec-A t=0 only)
#define STG_BASE  139264     // ring-store staging: [64][8] hi + lo = 2 KB
#define SMEM_SIZE 141312

// ws layout (bytes)
#define WS_FLAGS  0          // 132 flags, 64B apart: one writer per line
#define WS_BAR_SZ 16384
#define WS_BP     16384      // b' f32[1536]
#define WS_F0H    22528      // f0 hi bf16[64][64] (flat row-major)
#define WS_F0L    30720
#define WS_H0RH   65536      // h0 ring [32 slots][64 kblk][64 row][8 col] bf16 hi : 2 MB
#define WS_H0RL   2162688
#define WS_H1RH   4259840
#define WS_H1RL   6356992
#define WS_M      8454144    // M f32[1536][512]

// slot offset in ushorts for absolute step s
#define SLOT(s)   (((s) & (RSLOTS-1)) * 32768)

struct Params {
  const float *x, *f0;
  const float *eWih0,*eWhh0,*ebih0,*ebhh0,*eWih1,*eWhh1,*ebih1,*ebhh1;
  const float *dWih0,*dWhh0,*dbih0,*dbhh0,*dWih1,*dWhh1,*dbih1,*dbhh1;
  const float *fcW,*fcb;
  float* out;
  char* ws;
};

__device__ __forceinline__ ushort f2bf(float v){
  uint b = __float_as_uint(v);
  return (ushort)((b + 0x7FFFu + ((b >> 16) & 1u)) >> 16);
}
__device__ __forceinline__ float bf2f(ushort u){ return __uint_as_float(((uint)u) << 16); }

// ---------------- grid barrier: R11 exactly (validated best).
// One writer per 64B flag line; relaxed coherence-point polls, NO in-loop
// fences (1024-iter parachute); post-barrier acquire-inv every 16 rounds
// keeps plain cached ring reads fresh within the 32-slot reuse window.
__device__ __forceinline__ void gbar(uint* flags, uint r, int wg, int tid, bool rel, bool inv){
  __syncthreads();                                   // ring stores drained (vmcnt 0)
  if (tid == 0){
    if (rel) __builtin_amdgcn_fence(__ATOMIC_RELEASE, "agent");   // flush plain-stored staging
    __hip_atomic_store(&flags[wg*16], r, __ATOMIC_RELAXED, __HIP_MEMORY_SCOPE_AGENT);
  }
  asm volatile("" ::: "memory");
  if (tid < NWG){
    uint it = 0;
    while (__hip_atomic_load(&flags[tid*16], __ATOMIC_RELAXED, __HIP_MEMORY_SCOPE_AGENT) < r){
      __builtin_amdgcn_s_sleep(1);
      if ((++it & 1023u) == 0u) __builtin_amdgcn_fence(__ATOMIC_ACQUIRE, "agent");  // parachute only
    }
  }
  __syncthreads();
  if (inv) __builtin_amdgcn_fence(__ATOMIC_ACQUIRE, "agent");     // periodic L1/L2 invalidate
}

// ---------------- pack 2 gate-interleaved pair-tiles (32 slots x K) into LDS
template<int K>
__device__ void packW(char* lds, int base, const float* __restrict__ W, int colbase, int tid){
  for (int e = tid; e < 32*K; e += THREADS){
    int S = e / K, k = e - S*K;
    int gate = S & 3, hcl = S >> 2;
    float v = (gate < 3) ? W[(gate*H + colbase + hcl)*K + k] : 0.f;
    ushort hi = f2bf(v);
    ushort lo = f2bf(v - bf2f(hi));
    int tau = S >> 4, s = S & 15;
    int off = ((s*K + k)*2) ^ ((s & 7) << 4);
    char* tb = lds + base + tau*(16*K*4);
    *(ushort*)(tb + off) = hi;
    *(ushort*)(tb + 16*K*2 + off) = lo;
  }
}

__device__ void packFC(char* lds, const float* __restrict__ fcW, int colbase, int tid){
  for (int e = tid; e < 16*512; e += THREADS){
    int s = e >> 9, k = e & 511;
    float v = fcW[(colbase + s)*512 + k];
    ushort hi = f2bf(v);
    ushort lo = f2bf(v - bf2f(hi));
    int off = ((s*512 + k)*2) ^ ((s & 7) << 4);
    *(ushort*)(lds + off) = hi;
    *(ushort*)(lds + 16*512*2 + off) = lo;
  }
}

__device__ __forceinline__ void loadBias(const float* __restrict__ src, int colbase, int c, float* b){
#pragma unroll
  for (int tau = 0; tau < 2; ++tau){
    int gate = c & 3, hcl = 4*tau + (c >> 2);
    b[tau] = (gate < 3) ? src[gate*H + colbase + hcl] : 0.f;
  }
}

// blocked ring element (row, col): ushort offset (col>>3)*512 + row*8 + (col&7)
__device__ __forceinline__ void loadHold(const ushort* rh, const ushort* rl, int colb,
                                         int m, int lane, f32x4* hold){
  int c = lane & 15, g = lane >> 4;
#pragma unroll
  for (int tau = 0; tau < 2; ++tau){
    int col = colb + 4*tau + (c >> 2);
#pragma unroll
    for (int q = 0; q < 4; ++q){
      int row = m*16 + g*4 + q;
      int off = (col >> 3)*512 + row*8 + (col & 7);
      hold[tau][q] = bf2f(rh[off]) + bf2f(rl[off]);
    }
  }
}

// ---------------- 64xNTAU*16 GEMM tile, split-bf16 3-term, weights from LDS
// BLK=true: A in blocked ring layout [kblk][row][8] -> 16B loads at
// (kc*4+g)*512 + row*8.  BLK=false: flat row-major [64][K] (xT, f0 staging).
// All loads hoisted so the stream pipelines behind one latency.
template<int NTAU, int K, bool BLK>
__device__ __forceinline__ void gemm(const ushort* __restrict__ AH, const ushort* __restrict__ AL,
                                     const char* lds, int base, const float* bias,
                                     int m, int lane, f32x4* pre){
  const int c = lane & 15, g = lane >> 4;
  const int row = m*16 + c;
  constexpr int NK = K/32;
  bf16x8 ahv[NK], alv[NK];
#pragma unroll
  for (int kc = 0; kc < NK; ++kc){
    const int aoff = BLK ? ((kc*4 + g)*512 + row*8) : (row*K + kc*32 + g*8);
    ahv[kc] = *(const bf16x8*)(AH + aoff);
    alv[kc] = *(const bf16x8*)(AL + aoff);
  }
  f32x4 a1[NTAU], a2[NTAU];
#pragma unroll
  for (int tau = 0; tau < NTAU; ++tau){
    a1[tau] = f32x4{bias[tau], bias[tau], bias[tau], bias[tau]};
    a2[tau] = f32x4{0.f, 0.f, 0.f, 0.f};
  }
#pragma unroll
  for (int kc = 0; kc < NK; ++kc){
    const int off = ((c*K + kc*32 + g*8)*2) ^ ((c & 7) << 4);
#pragma unroll
    for (int tau = 0; tau < NTAU; ++tau){
      const char* tb = lds + base + tau*(16*K*4);
      bf16x8 wh = *(const bf16x8*)(tb + off);
      bf16x8 wl = *(const bf16x8*)(tb + 16*K*2 + off);
      a1[tau] = __builtin_amdgcn_mfma_f32_16x16x32_bf16(ahv[kc], wh, a1[tau], 0, 0, 0);
      a2[tau] = __builtin_amdgcn_mfma_f32_16x16x32_bf16(ahv[kc], wl, a2[tau], 0, 0, 0);
      a2[tau] = __builtin_amdgcn_mfma_f32_16x16x32_bf16(alv[kc], wh, a2[tau], 0, 0, 0);
    }
  }
#pragma unroll
  for (int tau = 0; tau < NTAU; ++tau) pre[tau] = a1[tau] + a2[tau];
}

// ---------------- GRU gates: compute hn, update hold, STAGE hi/lo tiles in LDS.
// (Replaces 1024 scattered 2-byte agent stores -> the R14 fix. Same values.)
__device__ __forceinline__ void gates_stage(const f32x4* pgi, const f32x4* pgh, f32x4* hold,
                                            ushort* __restrict__ stH, ushort* __restrict__ stL,
                                            int m, int lane){
  const int c = lane & 15, g = lane >> 4;
#pragma unroll
  for (int tau = 0; tau < 2; ++tau){
    f32x4 s, n, hn, rsh, zsh;
#pragma unroll
    for (int q = 0; q < 4; ++q) s[q] = 1.f / (1.f + expf(-(pgi[tau][q] + pgh[tau][q])));
#pragma unroll
    for (int q = 0; q < 4; ++q) rsh[q] = __shfl_xor(s[q], 2, 64);
#pragma unroll
    for (int q = 0; q < 4; ++q) zsh[q] = __shfl_xor(s[q], 3, 64);
#pragma unroll
    for (int q = 0; q < 4; ++q) n[q] = tanhf(pgi[tau][q] + rsh[q]*pgh[tau][q]);
#pragma unroll
    for (int q = 0; q < 4; ++q) hn[q] = (1.f - zsh[q])*n[q] + zsh[q]*hold[tau][q];
    hold[tau] = hn;
    if ((c & 3) == 2){
      const int cl = 4*tau + (c >> 2);                // local col 0..7
#pragma unroll
      for (int q = 0; q < 4; ++q){
        const int row = m*16 + g*4 + q;
        ushort hi = f2bf(hn[q]);
        ushort lo = f2bf(hn[q] - bf2f(hi));
        stH[row*8 + cl] = hi;
        stL[row*8 + cl] = lo;
      }
    }
  }
}

// ---------------- flush staged [64][8] tiles to the WG's contiguous 1KB ring
// blocks as coalesced 8B relaxed agent stores (32 FULL 64B lines per WG -
// no partial-line write-through RMW at the LLC). Call AFTER __syncthreads.
__device__ __forceinline__ void ring_flush(ushort* __restrict__ dH, ushort* __restrict__ dL,
                                           const ushort* __restrict__ stH,
                                           const ushort* __restrict__ stL, int tid){
  if (tid < 128){
    u64 v = *(const u64*)(stH + tid*4);
    __hip_atomic_store((u64*)dH + tid, v, __ATOMIC_RELAXED, __HIP_MEMORY_SCOPE_AGENT);
  } else if (tid < 256){
    int t2 = tid - 128;
    u64 v = *(const u64*)(stL + t2*4);
    __hip_atomic_store((u64*)dL + t2, v, __ATOMIC_RELAXED, __HIP_MEMORY_SCOPE_AGENT);
  }
}

__device__ __forceinline__ f32x4 bc4(float v){ return f32x4{v, v, v, v}; }

__global__ __launch_bounds__(THREADS, 1) void rnn_persist(Params p){
  extern __shared__ char smem[];
  char* ws = p.ws;
  uint* flags = (uint*)(ws + WS_FLAGS);
  float*  bp   = (float*)(ws + WS_BP);
  ushort* f0H  = (ushort*)(ws + WS_F0H);
  ushort* f0L  = (ushort*)(ws + WS_F0L);
  ushort* h0rH = (ushort*)(ws + WS_H0RH);
  ushort* h0rL = (ushort*)(ws + WS_H0RL);
  ushort* h1rH = (ushort*)(ws + WS_H1RH);
  ushort* h1rL = (ushort*)(ws + WS_H1RL);
  float*  Mw   = (float*)(ws + WS_M);
  ushort* xTH  = (ushort*)(void*)p.out;              // staged in d_out; dead before FC writes
  ushort* xTL  = xTH + TT*BQ*CIN;
  ushort* stH  = (ushort*)(smem + STG_BASE);         // [64][8] staging
  ushort* stL  = stH + 512;

  const int wg = blockIdx.x, tid = threadIdx.x;
  const int wid = tid >> 6, lane = tid & 63;
  const int c = lane & 15;
  const int gtid = wg*THREADS + tid;
  const int gstride = NWG*THREADS;
  uint bno = 0;

  // ================= prepass: xT (transpose+split), f0, M = dWih0@fcW, b'
  for (int e = gtid; e < TT*BQ*CIN; e += gstride){
    int t = e >> 12, b = (e >> 6) & 63, cc = e & 63;
    float v = p.x[(b*CIN + cc)*TT + t];
    ushort hi = f2bf(v);
    xTH[e] = hi; xTL[e] = f2bf(v - bf2f(hi));
  }
  for (int e = gtid; e < BQ*COUT; e += gstride){
    float v = p.f0[e];
    ushort hi = f2bf(v);
    f0H[e] = hi; f0L[e] = f2bf(v - bf2f(hi));
  }
  {
    const int total = 1536*512;
    const int per = (total + gstride - 1) / gstride;
    const int start = gtid * per;
    for (int i = 0; i < per; ++i){
      int e = start + i;
      if (e >= total) break;
      int rr = e >> 9, q = e & 511;
      float acc = 0.f;
      for (int k = 0; k < 64; ++k) acc += p.dWih0[rr*64 + k] * p.fcW[k*512 + q];
      Mw[e] = acc;
    }
  }
  for (int e = gtid; e < 1536; e += gstride){
    float acc = p.dbih0[e];
    for (int k = 0; k < 64; ++k) acc += p.dWih0[e*64 + k] * p.fcb[k];
    bp[e] = acc;
  }
  gbar(flags, ++bno, wg, tid, true, true);   // release staging + start clean

  // ================= pack encoder weights into LDS, load biases
  const bool isA = (wg < 64), isB = (wg >= 64 && wg < 128);
  const int colb = isA ? wg*8 : (wg - 64)*8;
  const int kblk = colb >> 3;                         // this WG's ring column-block
  float bgi[2] = {0.f,0.f}, bgh[2] = {0.f,0.f}, bgi0[2] = {0.f,0.f}, bfc = 0.f;
  f32x4 hold[2]; hold[0] = bc4(0.f); hold[1] = bc4(0.f);
  int fccol = 0;
  if (isA){
    packW<64 >(smem, GI_BASE, p.eWih0, colb, tid);
    packW<512>(smem, GH_BASE, p.eWhh0, colb, tid);
    loadBias(p.ebih0, colb, c, bgi); loadBias(p.ebhh0, colb, c, bgh);
  } else if (isB){
    packW<512>(smem, GI_BASE, p.eWih1, colb, tid);
    packW<512>(smem, GH_BASE, p.eWhh1, colb, tid);
    loadBias(p.ebih1, colb, c, bgi); loadBias(p.ebhh1, colb, c, bgh);
  } else {
    fccol = (wg - 128)*16;
    packFC(smem, p.fcW, fccol, tid);
    bfc = p.fcb[fccol + c];
  }
  gbar(flags, ++bno, wg, tid, false, false);

  // ================= encoder: 513 pipelined rounds (A: L0 @ t=r ; B: L1 @ t=r-1)
  for (int r = 0; r <= TT; ++r){
    if (isA && r < TT){
      const int t = r;
      f32x4 pgi[2], pgh[2];
      if (t > 0)
        gemm<2,512,true>(h0rH + SLOT(t-1), h0rL + SLOT(t-1), smem, GH_BASE, bgh, wid, lane, pgh);
      else { pgh[0] = bc4(bgh[0]); pgh[1] = bc4(bgh[1]); }
      gemm<2,64,false>(xTH + t*4096, xTL + t*4096, smem, GI_BASE, bgi, wid, lane, pgi);
      gates_stage(pgi, pgh, hold, stH, stL, wid, lane);
      __syncthreads();
      ring_flush(h0rH + SLOT(t) + kblk*512, h0rL + SLOT(t) + kblk*512, stH, stL, tid);
    } else if (isB && r >= 1){
      const int t = r - 1;
      f32x4 pgi[2], pgh[2];
      if (t > 0)
        gemm<2,512,true>(h1rH + SLOT(t-1), h1rL + SLOT(t-1), smem, GH_BASE, bgh, wid, lane, pgh);
      else { pgh[0] = bc4(bgh[0]); pgh[1] = bc4(bgh[1]); }
      gemm<2,512,true>(h0rH + SLOT(t), h0rL + SLOT(t), smem, GI_BASE, bgi, wid, lane, pgi);
      gates_stage(pgi, pgh, hold, stH, stL, wid, lane);
      __syncthreads();
      ring_flush(h1rH + SLOT(t) + kblk*512, h1rL + SLOT(t) + kblk*512, stH, stL, tid);
    }
    ++bno;
    gbar(flags, bno, wg, tid, false, (bno & 15u) == 0u);
  }

  // ================= repack decoder weights, reload state (enc finals = step 511)
  if (isA){
    packW<512>(smem, GH_BASE, p.dWhh0, colb, tid);
    packW<512>(smem, GI_BASE, Mw,      colb, tid);   // folded FC->L0 input weights
    packW<64 >(smem, GI0_BASE, p.dWih0, colb, tid);
    loadBias(bp,      colb, c, bgi);
    loadBias(p.dbhh0, colb, c, bgh);
    loadBias(p.dbih0, colb, c, bgi0);
    loadHold(h0rH + SLOT(511), h0rL + SLOT(511), colb, wid, lane, hold);
  } else if (isB){
    packW<512>(smem, GI_BASE, p.dWih1, colb, tid);
    packW<512>(smem, GH_BASE, p.dWhh1, colb, tid);
    loadBias(p.dbih1, colb, c, bgi); loadBias(p.dbhh1, colb, c, bgh);
    loadHold(h1rH + SLOT(511), h1rL + SLOT(511), colb, wid, lane, hold);
  }
  gbar(flags, ++bno, wg, tid, false, true);          // phase transition: force inv

  // ================= decoder: 1025 rounds; A fires even r (step g=512+t), B odd.
  // Off-parity rounds precompute the recurrent half (operand one round old).
  f32x4 pgh_s[2]; pgh_s[0] = bc4(0.f); pgh_s[1] = bc4(0.f);
  for (int r = 0; r <= 2*TT; ++r){
    if (isA){
      if (r == 0){
        gemm<2,512,true>(h0rH + SLOT(511), h0rL + SLOT(511), smem, GH_BASE, bgh, wid, lane, pgh_s);
        f32x4 pgi[2];
        gemm<2,64,false>(f0H, f0L, smem, GI0_BASE, bgi0, wid, lane, pgi);
        gates_stage(pgi, pgh_s, hold, stH, stL, wid, lane);
        __syncthreads();
        ring_flush(h0rH + SLOT(512) + kblk*512, h0rL + SLOT(512) + kblk*512, stH, stL, tid);
      } else if (r & 1){
        const int t = (r + 1) >> 1;                  // prefetch gh for next step: h0^{511+t}
        if (t < TT) gemm<2,512,true>(h0rH + SLOT(511+t), h0rL + SLOT(511+t), smem, GH_BASE, bgh, wid, lane, pgh_s);
      } else {
        const int t = r >> 1;
        if (t < TT){
          f32x4 pgi[2];
          gemm<2,512,true>(h1rH + SLOT(511+t), h1rL + SLOT(511+t), smem, GI_BASE, bgi, wid, lane, pgi);
          gates_stage(pgi, pgh_s, hold, stH, stL, wid, lane);
          __syncthreads();
          ring_flush(h0rH + SLOT(512+t) + kblk*512, h0rL + SLOT(512+t) + kblk*512, stH, stL, tid);
        }
      }
    } else if (isB){
      if (!(r & 1)){
        const int t = r >> 1;                        // prefetch gh: h1^{511+t}
        if (t < TT) gemm<2,512,true>(h1rH + SLOT(511+t), h1rL + SLOT(511+t), smem, GH_BASE, bgh, wid, lane, pgh_s);
      } else {
        const int t = r >> 1;
        f32x4 pgi[2];
        gemm<2,512,true>(h0rH + SLOT(512+t), h0rL + SLOT(512+t), smem, GI_BASE, bgi, wid, lane, pgi);
        gates_stage(pgi, pgh_s, hold, stH, stL, wid, lane);
        __syncthreads();
        ring_flush(h1rH + SLOT(512+t) + kblk*512, h1rL + SLOT(512+t) + kblk*512, stH, stL, tid);
      }
    } else {
      if (!(r & 1) && r >= 2){
        const int t = (r - 2) >> 1;                  // FC head, 2 rounds late: h1^{512+t}
        f32x4 pre[1];
        gemm<1,512,true>(h1rH + SLOT(512+t), h1rL + SLOT(512+t), smem, 0, &bfc, wid, lane, pre);
        const int outcol = fccol + c, gq = lane >> 4;
#pragma unroll
        for (int q = 0; q < 4; ++q){
          const int row = wid*16 + gq*4 + q;
          p.out[(row*COUT + outcol)*TT + t] = pre[0][q];
        }
      }
    }
    ++bno;
    gbar(flags, bno, wg, tid, false, (bno & 15u) == 0u);
  }
}

extern "C" void kernel_launch(void* const* d_in, const int* in_sizes, int n_in,
                              void* d_out, int out_size, void* d_ws, size_t ws_size,
                              hipStream_t stream){
  Params p;
  p.x     = (const float*)d_in[0];  p.f0    = (const float*)d_in[1];
  p.eWih0 = (const float*)d_in[2];  p.eWhh0 = (const float*)d_in[3];
  p.ebih0 = (const float*)d_in[4];  p.ebhh0 = (const float*)d_in[5];
  p.eWih1 = (const float*)d_in[6];  p.eWhh1 = (const float*)d_in[7];
  p.ebih1 = (const float*)d_in[8];  p.ebhh1 = (const float*)d_in[9];
  p.dWih0 = (const float*)d_in[10]; p.dWhh0 = (const float*)d_in[11];
  p.dbih0 = (const float*)d_in[12]; p.dbhh0 = (const float*)d_in[13];
  p.dWih1 = (const float*)d_in[14]; p.dWhh1 = (const float*)d_in[15];
  p.dbih1 = (const float*)d_in[16]; p.dbhh1 = (const float*)d_in[17];
  p.fcW   = (const float*)d_in[18]; p.fcb   = (const float*)d_in[19];
  p.out = (float*)d_out;
  p.ws  = (char*)d_ws;

  hipFuncSetAttribute((const void*)rnn_persist, hipFuncAttributeMaxDynamicSharedMemorySize, SMEM_SIZE);
  hipMemsetAsync(d_ws, 0, WS_BAR_SZ, stream);   // reset barrier flags each launch
  hipLaunchKernelGGL(rnn_persist, dim3(NWG), dim3(THREADS), SMEM_SIZE, stream, p);
}